// Round 1
// baseline (259.016 us; speedup 1.0000x reference)
//
#include <hip/hip_runtime.h>

// Problem constants (from reference)
#define NHEADS 8
#define TQ 4
#define QH 16
#define QW 16
#define TK 4
#define KH 16
#define KW 16
#define DIM 64
#define BATCH 4

// One block per q-row: row = ((b*NHEADS + n)*1024 + t*256 + h*16 + w)
// Each row produces 1024 outputs: out[tk*256 + kh*16 + kw]
//   = scores[row, idx] + dot(q, hemb[h-kh+15]) + dot(q, wemb[w-kw+15]) + dot(q, temb[t-tk+3])
__global__ __launch_bounds__(256) void relpos_kernel(
    const float* __restrict__ query,   // [B,H,1024,64]
    const float* __restrict__ scores,  // [B,H,1024,1024]
    const float* __restrict__ hemb,    // [31,64]
    const float* __restrict__ wemb,    // [31,64]
    const float* __restrict__ temb,    // [7,64]
    float* __restrict__ out)           // [B,H,1024,1024]
{
    const int row = blockIdx.x;        // 0..32767
    const int pos = row & 1023;
    const int t = pos >> 8;
    const int h = (pos >> 4) & 15;
    const int w = pos & 15;

    __shared__ float q[DIM];
    __shared__ float rel[36];          // [0:16)=rel_h, [16:32)=rel_w, [32:36)=rel_t

    const int tid = threadIdx.x;
    if (tid < DIM) q[tid] = query[(size_t)row * DIM + tid];
    __syncthreads();

    if (tid < 36) {
        const float* emb;
        int r;
        if (tid < 16)      { emb = hemb; r = h - tid + 15; }
        else if (tid < 32) { emb = wemb; r = w - (tid - 16) + 15; }
        else               { emb = temb; r = t - (tid - 32) + 3; }
        const float4* e4 = (const float4*)(emb + (size_t)r * DIM);
        float acc = 0.f;
#pragma unroll
        for (int c = 0; c < DIM / 4; ++c) {
            float4 ev = e4[c];
            acc += q[4 * c + 0] * ev.x + q[4 * c + 1] * ev.y
                 + q[4 * c + 2] * ev.z + q[4 * c + 3] * ev.w;
        }
        rel[tid] = acc;
    }
    __syncthreads();

    // 1024 outputs per row, 4 consecutive per thread (same tk, same kh, kw run)
    const int base = tid << 2;         // 0..1020, multiple of 4
    const int tk  = base >> 8;
    const int kh  = (base >> 4) & 15;
    const int kw0 = base & 15;         // in {0,4,8,12}

    const float add_hk = rel[kh] + rel[32 + tk];
    const float4 s = *(const float4*)(scores + (size_t)row * 1024 + base);
    float4 o;
    o.x = s.x + add_hk + rel[16 + kw0 + 0];
    o.y = s.y + add_hk + rel[16 + kw0 + 1];
    o.z = s.z + add_hk + rel[16 + kw0 + 2];
    o.w = s.w + add_hk + rel[16 + kw0 + 3];
    *(float4*)(out + (size_t)row * 1024 + base) = o;
}

extern "C" void kernel_launch(void* const* d_in, const int* in_sizes, int n_in,
                              void* d_out, int out_size, void* d_ws, size_t ws_size,
                              hipStream_t stream) {
    const float* query  = (const float*)d_in[0];
    const float* scores = (const float*)d_in[1];
    const float* hemb   = (const float*)d_in[2];
    const float* wemb   = (const float*)d_in[3];
    const float* temb   = (const float*)d_in[4];
    float* out = (float*)d_out;

    const int rows = BATCH * NHEADS * TQ * QH * QW;  // 32768
    relpos_kernel<<<dim3(rows), dim3(256), 0, stream>>>(query, scores, hemb, wemb, temb, out);
}

// Round 2
// 250.955 us; speedup vs baseline: 1.0321x; 1.0321x over previous
//
#include <hip/hip_runtime.h>

#define NHEADS 8
#define TQ 4
#define QH 16
#define QW 16
#define TK 4
#define KH 16
#define KW 16
#define DIM 64
#define BATCH 4

// One block per 4 consecutive q-rows. Rows 4b..4b+3 share t,h; w = w0..w0+3.
// out[row][tk*256+kh*16+kw] = scores[row][...] + dot(q_row, hemb[h-kh+15])
//                            + dot(q_row, wemb[w-kw+15]) + dot(q_row, temb[t-tk+3])
__global__ __launch_bounds__(256) void relpos_kernel(
    const float* __restrict__ query,   // [B,H,1024,64]
    const float* __restrict__ scores,  // [B,H,1024,1024]
    const float* __restrict__ hemb,    // [31,64]
    const float* __restrict__ wemb,    // [31,64]
    const float* __restrict__ temb,    // [7,64]
    float* __restrict__ out)           // [B,H,1024,1024]
{
    const int tid  = threadIdx.x;
    const int row0 = blockIdx.x << 2;   // 4 rows per block, 1024%4==0 so same t,h
    const int pos  = row0 & 1023;
    const int t  = pos >> 8;
    const int h  = (pos >> 4) & 15;
    const int w0 = pos & 15;            // multiple of 4; rows have w = w0+r

    // Phase 1: issue all score loads up front (4 float4 in flight per thread)
    const float4* sc4 = (const float4*)(scores + (size_t)row0 * 1024);
    float4 s0 = sc4[tid];
    float4 s1 = sc4[256 + tid];
    float4 s2 = sc4[512 + tid];
    float4 s3 = sc4[768 + tid];

    __shared__ float rel[4][36];        // per row: [0:16)=rel_h, [16:32)=rel_w, [32:36)=rel_t

    // Phase 2: 144 threads compute the 4x36 bias dots (q + emb straight from
    // global; 1 KB q region + ~9 KB emb rows are L1-hot). Overlaps the score loads.
    if (tid < 144) {
        const int r = tid / 36;
        const int j = tid - r * 36;
        const float* emb;
        int e;
        if (j < 16)      { emb = hemb; e = h - j + 15; }
        else if (j < 32) { emb = wemb; e = (w0 + r) - (j - 16) + 15; }
        else             { emb = temb; e = t - (j - 32) + 3; }
        const float4* e4 = (const float4*)(emb + (size_t)e * DIM);
        const float4* q4 = (const float4*)(query + (size_t)(row0 + r) * DIM);
        float acc = 0.f;
#pragma unroll
        for (int c = 0; c < DIM / 4; ++c) {
            float4 qv = q4[c];
            float4 ev = e4[c];
            acc += qv.x * ev.x + qv.y * ev.y + qv.z * ev.z + qv.w * ev.w;
        }
        rel[r][j] = acc;
    }
    __syncthreads();                    // the only barrier

    // Phase 3: combine + store. Thread handles floats [4*tid, 4*tid+4) of each row.
    const int base = tid << 2;
    const int tk  = base >> 8;
    const int kh  = (base >> 4) & 15;
    const int kw0 = base & 15;

    float4* o4 = (float4*)(out + (size_t)row0 * 1024);
#pragma unroll
    for (int r = 0; r < 4; ++r) {
        const float4 s = (r == 0) ? s0 : (r == 1) ? s1 : (r == 2) ? s2 : s3;
        const float a = rel[r][kh] + rel[r][32 + tk];
        float4 o;
        o.x = s.x + a + rel[r][16 + kw0 + 0];
        o.y = s.y + a + rel[r][16 + kw0 + 1];
        o.z = s.z + a + rel[r][16 + kw0 + 2];
        o.w = s.w + a + rel[r][16 + kw0 + 3];
        o4[r * 256 + tid] = o;
    }
}

extern "C" void kernel_launch(void* const* d_in, const int* in_sizes, int n_in,
                              void* d_out, int out_size, void* d_ws, size_t ws_size,
                              hipStream_t stream) {
    const float* query  = (const float*)d_in[0];
    const float* scores = (const float*)d_in[1];
    const float* hemb   = (const float*)d_in[2];
    const float* wemb   = (const float*)d_in[3];
    const float* temb   = (const float*)d_in[4];
    float* out = (float*)d_out;

    const int rows = BATCH * NHEADS * TQ * QH * QW;  // 32768
    relpos_kernel<<<dim3(rows / 4), dim3(256), 0, stream>>>(query, scores, hemb, wemb, temb, out);
}